// Round 1
// baseline (801.460 us; speedup 1.0000x reference)
//
#include <hip/hip_runtime.h>

#define NN 20000      // nodes
#define NE 320000     // edges
#define SS 2          // feature axis
#define FIN 128
#define FH 246

// ---------------- degree histogram ----------------
__global__ void degree_kernel(const int* __restrict__ src, const int* __restrict__ dst,
                              int* __restrict__ deg_out, int* __restrict__ deg_in) {
    int e = blockIdx.x * blockDim.x + threadIdx.x;
    if (e < NE) {
        atomicAdd(&deg_out[src[e]], 1);
        atomicAdd(&deg_in[dst[e]], 1);
    }
}

// ---------------- norms ----------------
__global__ void norm_kernel(const int* __restrict__ deg_out, const int* __restrict__ deg_in,
                            float* __restrict__ norm_out, float* __restrict__ norm_in) {
    int n = blockIdx.x * blockDim.x + threadIdx.x;
    if (n < NN) {
        norm_out[n] = rsqrtf(fmaxf((float)deg_out[n], 1.0f));
        norm_in[n]  = rsqrtf(fmaxf((float)deg_in[n], 1.0f));
    }
}

// ---------------- exclusive scan of in-degrees -> row_ptr (single block) ----------------
__global__ void scan_kernel(const int* __restrict__ deg_in, int* __restrict__ row_ptr,
                            int* __restrict__ cursor) {
    __shared__ int smem[256];
    __shared__ int carry_s;
    int tid = threadIdx.x;
    if (tid == 0) carry_s = 0;
    __syncthreads();
    for (int base = 0; base < NN; base += 256) {
        int i = base + tid;
        int v = (i < NN) ? deg_in[i] : 0;
        smem[tid] = v;
        __syncthreads();
        for (int off = 1; off < 256; off <<= 1) {
            int t = (tid >= off) ? smem[tid - off] : 0;
            __syncthreads();
            smem[tid] += t;
            __syncthreads();
        }
        int incl  = smem[tid];
        int total = smem[255];
        int carry = carry_s;
        if (i < NN) {
            int excl = carry + incl - v;
            row_ptr[i] = excl;
            cursor[i]  = excl;
        }
        __syncthreads();
        if (tid == 0) carry_s = carry + total;
        __syncthreads();
    }
    if (tid == 0) row_ptr[NN] = carry_s;
}

// ---------------- scatter edges into CSR ----------------
__global__ void scatter_kernel(const int* __restrict__ src, const int* __restrict__ dst,
                               int* __restrict__ cursor, int* __restrict__ sorted_src) {
    int e = blockIdx.x * blockDim.x + threadIdx.x;
    if (e < NE) {
        int d = dst[e];
        int pos = atomicAdd(&cursor[d], 1);
        sorted_src[pos] = src[e];
    }
}

// ---------------- per-dst gather-aggregate: agg[n,s,f] = sum_{e: dst=n} h[src,s,f]*norm_out[src]
template<int F>
__global__ void aggregate_kernel(const float* __restrict__ h,
                                 const int* __restrict__ row_ptr,
                                 const int* __restrict__ sorted_src,
                                 const float* __restrict__ norm_out,
                                 float* __restrict__ agg) {
    int n = blockIdx.x;
    int f = threadIdx.x;
    int beg = row_ptr[n], end = row_ptr[n + 1];
    float acc0 = 0.f, acc1 = 0.f;
    for (int i = beg; i < end; ++i) {
        int s = sorted_src[i];
        float nrm = norm_out[s];
        if (f < F) {
            const float* hp = h + (size_t)s * (2 * F);
            acc0 += hp[f]     * nrm;
            acc1 += hp[F + f] * nrm;
        }
    }
    if (f < F) {
        float* ap = agg + (size_t)n * (2 * F);
        ap[f]     = acc0;
        ap[F + f] = acc1;
    }
}

// ---------------- GEMM: out[m,j] = relu( (A[m,:]*norm_in[m/2]) . W[:,j] + b[j] ), Nout=246
template<int K>
__global__ __launch_bounds__(256) void gemm_kernel(const float* __restrict__ A,
                                                   const float* __restrict__ W,
                                                   const float* __restrict__ b,
                                                   const float* __restrict__ norm_in,
                                                   float* __restrict__ out) {
    constexpr int ROWS = 16;
    __shared__ float a_s[ROWS * K];
    int m0 = blockIdx.x * ROWS;
    int tid = threadIdx.x;
    for (int idx = tid; idx < ROWS * K; idx += 256) {
        int r = idx / K;
        int k = idx - r * K;
        int m = m0 + r;
        a_s[idx] = A[(size_t)m * K + k] * norm_in[m >> 1];
    }
    __syncthreads();
    int j = tid;
    if (j < 246) {
        float acc[ROWS];
#pragma unroll
        for (int r = 0; r < ROWS; ++r) acc[r] = 0.f;
        for (int k = 0; k < K; ++k) {
            float wv = W[k * 246 + j];
#pragma unroll
            for (int r = 0; r < ROWS; ++r) acc[r] += a_s[r * K + k] * wv;
        }
        float bj = b[j];
#pragma unroll
        for (int r = 0; r < ROWS; ++r) {
            float v = acc[r] + bj;
            out[(size_t)(m0 + r) * 246 + j] = v > 0.f ? v : 0.f;
        }
    }
}

// ---------------- epilogue: out[n] = mean_s(h[n,s,:]) . fc_w + fc_b ----------------
__global__ void final_kernel(const float* __restrict__ h,
                             const float* __restrict__ fcw, const float* __restrict__ fcb,
                             float* __restrict__ out) {
    int n = blockIdx.x;
    int lane = threadIdx.x;
    float acc = 0.f;
    for (int f = lane; f < FH; f += 64) {
        acc += (h[(size_t)n * (2 * FH) + f] + h[(size_t)n * (2 * FH) + FH + f]) * fcw[f];
    }
#pragma unroll
    for (int off = 32; off > 0; off >>= 1)
        acc += __shfl_down(acc, off, 64);
    if (lane == 0) out[n] = 0.5f * acc + fcb[0];
}

extern "C" void kernel_launch(void* const* d_in, const int* in_sizes, int n_in,
                              void* d_out, int out_size, void* d_ws, size_t ws_size,
                              hipStream_t stream) {
    const float* feat = (const float*)d_in[0];
    const int*   src  = (const int*)d_in[1];
    const int*   dst  = (const int*)d_in[2];
    const float* W0   = (const float*)d_in[3];
    const float* b0   = (const float*)d_in[4];
    const float* W1   = (const float*)d_in[5];
    const float* b1   = (const float*)d_in[6];
    const float* W2   = (const float*)d_in[7];
    const float* b2   = (const float*)d_in[8];
    const float* fcw  = (const float*)d_in[9];
    const float* fcb  = (const float*)d_in[10];
    float* out = (float*)d_out;

    char* ws = (char*)d_ws;
    size_t off = 0;
    auto alloc = [&](size_t bytes) {
        void* p = ws + off;
        off = (off + bytes + 255) & ~(size_t)255;
        return p;
    };
    int*   deg_out_i = (int*)alloc(2 * NN * sizeof(int));   // deg_out + deg_in adjacent
    int*   deg_in_i  = deg_out_i + NN;
    int*   row_ptr   = (int*)alloc((NN + 1) * sizeof(int));
    int*   cursor    = (int*)alloc(NN * sizeof(int));
    int*   sorted    = (int*)alloc(NE * sizeof(int));
    float* norm_out  = (float*)alloc(NN * sizeof(float));
    float* norm_in   = (float*)alloc(NN * sizeof(float));
    float* bufA      = (float*)alloc((size_t)NN * SS * FH * sizeof(float));
    float* bufB      = (float*)alloc((size_t)NN * SS * FH * sizeof(float));

    // zero degree counters (ws is poisoned 0xAA before every call)
    hipMemsetAsync(deg_out_i, 0, 2 * NN * sizeof(int), stream);

    degree_kernel<<<(NE + 255) / 256, 256, 0, stream>>>(src, dst, deg_out_i, deg_in_i);
    norm_kernel<<<(NN + 255) / 256, 256, 0, stream>>>(deg_out_i, deg_in_i, norm_out, norm_in);
    scan_kernel<<<1, 256, 0, stream>>>(deg_in_i, row_ptr, cursor);
    scatter_kernel<<<(NE + 255) / 256, 256, 0, stream>>>(src, dst, cursor, sorted);

    // Layer 0: features [N,S,128] -> agg(bufA) -> gemm -> h1(bufB) [N,S,246]
    aggregate_kernel<FIN><<<NN, 128, 0, stream>>>(feat, row_ptr, sorted, norm_out, bufA);
    gemm_kernel<FIN><<<(NN * SS) / 16, 256, 0, stream>>>(bufA, W0, b0, norm_in, bufB);

    // Layer 1
    aggregate_kernel<FH><<<NN, 256, 0, stream>>>(bufB, row_ptr, sorted, norm_out, bufA);
    gemm_kernel<FH><<<(NN * SS) / 16, 256, 0, stream>>>(bufA, W1, b1, norm_in, bufB);

    // Layer 2
    aggregate_kernel<FH><<<NN, 256, 0, stream>>>(bufB, row_ptr, sorted, norm_out, bufA);
    gemm_kernel<FH><<<(NN * SS) / 16, 256, 0, stream>>>(bufA, W2, b2, norm_in, bufB);

    // Epilogue
    final_kernel<<<NN, 64, 0, stream>>>(bufB, fcw, fcb, out);
}